// Round 3
// baseline (392.211 us; speedup 1.0000x reference)
//
#include <hip/hip_runtime.h>
#include <hip/hip_bf16.h>

#define NPTS  4096
#define BATCH 4
#define KK    16
#define CH    64

// ---------------------------------------------------------------------------
// Kernel A: exact KNN (k+1 smallest, matching jax.lax.top_k tie-break by
// lowest index; pass 0 is the self point, dropped).
// One wave per query point; 4 waves (256 threads) per block; per-wave private
// LDS distance array. Lane-strided layout (j = t*64 + lane) -> 2-way bank
// aliasing only (free on CDNA4).
// ---------------------------------------------------------------------------
__global__ __launch_bounds__(256) void knn_kernel(const float* __restrict__ xyz,
                                                  int* __restrict__ knn_idx) {
    __shared__ float dist[4][NPTS];
    const int wave = threadIdx.x >> 6;
    const int lane = threadIdx.x & 63;
    const int q = blockIdx.x * 4 + wave;        // global query index in [0, B*N)
    const int b = q >> 12;                      // / NPTS
    const int i = q & (NPTS - 1);
    const float* xb = xyz + (size_t)b * NPTS * 3;
    const float qx = xb[i * 3 + 0];
    const float qy = xb[i * 3 + 1];
    const float qz = xb[i * 3 + 2];
    float* ld = dist[wave];

    // Distance computation. Disable FMA contraction so rounding matches the
    // reference's (mul, mul, mul, add, add) order exactly — a 1-ulp
    // difference at the k-th-neighbor boundary swaps a neighbor.
    {
#pragma clang fp contract(off)
#pragma unroll 4
        for (int t = 0; t < 64; ++t) {
            const int j = t * 64 + lane;
            const float dx = xb[j * 3 + 0] - qx;
            const float dy = xb[j * 3 + 1] - qy;
            const float dz = xb[j * 3 + 2] - qz;
            const float sx = dx * dx;
            const float sy = dy * dy;
            const float sz = dz * dz;
            ld[j] = (sx + sy) + sz;
        }
    }
    __syncthreads();

    int my_nbr = 0;
    for (int pass = 0; pass < KK + 1; ++pass) {
        float dmin = 3.4e38f;
        int tmin = 0;
        // strict '<' keeps the earliest t => lowest j within the lane
#pragma unroll
        for (int t = 0; t < 64; ++t) {
            const float d = ld[t * 64 + lane];
            if (d < dmin) { dmin = d; tmin = t; }
        }
        int jmin = tmin * 64 + lane;
        // butterfly reduce across 64 lanes; tie-break: lower index wins
#pragma unroll
        for (int off = 32; off > 0; off >>= 1) {
            const float d2 = __shfl_xor(dmin, off);
            const int   j2 = __shfl_xor(jmin, off);
            if (d2 < dmin || (d2 == dmin && j2 < jmin)) { dmin = d2; jmin = j2; }
        }
        // knock out the winner for the next pass
        if (lane == (jmin & 63)) ld[jmin] = 3.4e38f;
        // passes 1..16 are the neighbors (pass 0 == self, dist 0)
        if (pass == lane + 1) my_nbr = jmin;
        __syncthreads();
    }
    if (lane < KK) knn_idx[(size_t)q * KK + lane] = my_nbr;
}

// ---------------------------------------------------------------------------
// Kernel B: gather relative coords, 3-layer MLP (relu, relu, none), max over
// the 16 neighbors. One wave per point, lane = output channel.
// W2/W3 staged transposed in LDS (conflict-free per-lane column reads);
// H1/H2 staged per-wave in LDS rows of stride 20 floats (16B aligned) read
// back as b128 broadcasts.
// ---------------------------------------------------------------------------
__global__ __launch_bounds__(256) void mlp_kernel(const float* __restrict__ xyz,
                                                  const int* __restrict__ knn_idx,
                                                  const float* __restrict__ w1,
                                                  const float* __restrict__ w2,
                                                  const float* __restrict__ w3,
                                                  float* __restrict__ out) {
    __shared__ float w2t[CH * CH];                    // w2t[cp*64 + c] = w2[c][cp]
    __shared__ float w3t[CH * CH];
    __shared__ __align__(16) float hbuf[4][2][CH][20]; // per-wave H1/H2, [c'][nb]
    __shared__ float gbuf[4][KK][4];                  // per-wave rel coords
    __shared__ float obuf[CH][17];                    // block output staging

    const int wave = threadIdx.x >> 6;
    const int lane = threadIdx.x & 63;
    const int base = blockIdx.x * 16;                 // 16 points per block
    const int b = base >> 12;
    const int n0 = base & (NPTS - 1);
    const float* xb = xyz + (size_t)b * NPTS * 3;

    for (int s = threadIdx.x; s < CH * CH; s += 256) {
        const int c = s >> 6, cp = s & 63;
        w2t[cp * CH + c] = w2[s];
        w3t[cp * CH + c] = w3[s];
    }
    const float w1c0 = w1[lane * 3 + 0];
    const float w1c1 = w1[lane * 3 + 1];
    const float w1c2 = w1[lane * 3 + 2];
    __syncthreads();

    for (int r = 0; r < 4; ++r) {
        const int p = wave * 4 + r;                   // point slot 0..15
        const int n = n0 + p;
        // ---- gather relative neighbor coords (lanes 0..15) ----
        if (lane < KK) {
            const int j = knn_idx[((size_t)b * NPTS + n) * KK + lane];
            const float px = xb[n * 3 + 0];
            const float py = xb[n * 3 + 1];
            const float pz = xb[n * 3 + 2];
            gbuf[wave][lane][0] = xb[j * 3 + 0] - px;
            gbuf[wave][lane][1] = xb[j * 3 + 1] - py;
            gbuf[wave][lane][2] = xb[j * 3 + 2] - pz;
        }
        __syncthreads();
        // ---- layer 1: h1[c][nb] = relu(W1 row c . g[nb]) ----
        float h1[KK];
#pragma unroll
        for (int nb = 0; nb < KK; ++nb) {
            const float gx = gbuf[wave][nb][0];
            const float gy = gbuf[wave][nb][1];
            const float gz = gbuf[wave][nb][2];
            const float v = w1c0 * gx + w1c1 * gy + w1c2 * gz;
            h1[nb] = v > 0.f ? v : 0.f;
        }
#pragma unroll
        for (int nb4 = 0; nb4 < 4; ++nb4) {
            *(float4*)&hbuf[wave][0][lane][nb4 * 4] =
                make_float4(h1[nb4 * 4 + 0], h1[nb4 * 4 + 1],
                            h1[nb4 * 4 + 2], h1[nb4 * 4 + 3]);
        }
        __syncthreads();
        // ---- layer 2: h2 = relu(W2 h1) ----
        float h2[KK];
#pragma unroll
        for (int nb = 0; nb < KK; ++nb) h2[nb] = 0.f;
#pragma unroll 4
        for (int cp = 0; cp < CH; ++cp) {
            const float w = w2t[cp * CH + lane];      // per-lane, conflict-free
            float a[KK];
            *(float4*)&a[0]  = *(const float4*)&hbuf[wave][0][cp][0];   // broadcast
            *(float4*)&a[4]  = *(const float4*)&hbuf[wave][0][cp][4];
            *(float4*)&a[8]  = *(const float4*)&hbuf[wave][0][cp][8];
            *(float4*)&a[12] = *(const float4*)&hbuf[wave][0][cp][12];
#pragma unroll
            for (int nb = 0; nb < KK; ++nb) h2[nb] += w * a[nb];
        }
#pragma unroll
        for (int nb = 0; nb < KK; ++nb) h2[nb] = h2[nb] > 0.f ? h2[nb] : 0.f;
#pragma unroll
        for (int nb4 = 0; nb4 < 4; ++nb4) {
            *(float4*)&hbuf[wave][1][lane][nb4 * 4] =
                make_float4(h2[nb4 * 4 + 0], h2[nb4 * 4 + 1],
                            h2[nb4 * 4 + 2], h2[nb4 * 4 + 3]);
        }
        __syncthreads();
        // ---- layer 3: h3 = W3 h2 (no relu), then max over neighbors ----
        float h3[KK];
#pragma unroll
        for (int nb = 0; nb < KK; ++nb) h3[nb] = 0.f;
#pragma unroll 4
        for (int cp = 0; cp < CH; ++cp) {
            const float w = w3t[cp * CH + lane];
            float a[KK];
            *(float4*)&a[0]  = *(const float4*)&hbuf[wave][1][cp][0];
            *(float4*)&a[4]  = *(const float4*)&hbuf[wave][1][cp][4];
            *(float4*)&a[8]  = *(const float4*)&hbuf[wave][1][cp][8];
            *(float4*)&a[12] = *(const float4*)&hbuf[wave][1][cp][12];
#pragma unroll
            for (int nb = 0; nb < KK; ++nb) h3[nb] += w * a[nb];
        }
        float m = h3[0];
#pragma unroll
        for (int nb = 1; nb < KK; ++nb) m = fmaxf(m, h3[nb]);
        obuf[lane][p] = m;
    }
    __syncthreads();
    // coalesced-ish output store: out[(b*CH + c)*NPTS + n0 + p]
    for (int s = threadIdx.x; s < CH * 16; s += 256) {
        const int c = s >> 4, pp = s & 15;
        out[((size_t)(b * CH + c)) * NPTS + n0 + pp] = obuf[c][pp];
    }
}

extern "C" void kernel_launch(void* const* d_in, const int* in_sizes, int n_in,
                              void* d_out, int out_size, void* d_ws, size_t ws_size,
                              hipStream_t stream) {
    (void)in_sizes; (void)n_in; (void)out_size; (void)ws_size;
    const float* xyz = (const float*)d_in[0];
    const float* w1  = (const float*)d_in[1];
    const float* w2  = (const float*)d_in[2];
    const float* w3  = (const float*)d_in[3];
    // d_in[4] is k (always 16 for this problem)
    int*   knn = (int*)d_ws;                 // BATCH*NPTS*KK ints = 1 MiB
    float* out = (float*)d_out;

    knn_kernel<<<BATCH * NPTS / 4, 256, 0, stream>>>(xyz, knn);
    mlp_kernel<<<BATCH * NPTS / 16, 256, 0, stream>>>(xyz, knn, w1, w2, w3, out);
}

// Round 4
// 221.465 us; speedup vs baseline: 1.7710x; 1.7710x over previous
//
#include <hip/hip_runtime.h>
#include <hip/hip_bf16.h>

#define NPTS  4096
#define BATCH 4
#define KK    16
#define CH    64
#define SURV_CAP 64

// ---------------------------------------------------------------------------
// Kernel A: exact KNN via pivot + compact + bitonic sort.
// One wave per query. Per-lane 64 distances in VGPRs (exact reference
// arithmetic, contract off). Pivot T = 17th smallest of the 64 lane-minima
// (provably >= 17th smallest overall, so survivors {d<=T} contain the true
// top-17). Survivors (~20) ballot-compacted to a 512B per-wave LDS buffer,
// then bitonic-sorted as (d_bits<<32)|j u64 keys == top_k's (dist, index)
// ordering. Lane 0 after sort = self (dropped); lanes 1..16 = neighbors.
// Overflow (>64 survivors, impossible for this data) falls back to an exact
// in-register lexicographic successive-min so correctness never depends on
// the pivot.
// ---------------------------------------------------------------------------
__global__ __launch_bounds__(256) void knn_kernel(const float* __restrict__ xyz,
                                                  int* __restrict__ knn_idx) {
    __shared__ unsigned long long sbuf[4][SURV_CAP];
    const int wave = threadIdx.x >> 6;
    const int lane = threadIdx.x & 63;
    const int q = blockIdx.x * 4 + wave;        // global query in [0, B*N)
    const int b = q >> 12;
    const int i = q & (NPTS - 1);
    const float* xb = xyz + (size_t)b * NPTS * 3;
    const float qx = xb[i * 3 + 0];
    const float qy = xb[i * 3 + 1];
    const float qz = xb[i * 3 + 2];

    // ---- distances, kept in VGPRs (static indexing via full unroll) ----
    float d[64];
    {
#pragma clang fp contract(off)
#pragma unroll
        for (int t = 0; t < 64; ++t) {
            const int j = t * 64 + lane;
            const float dx = xb[j * 3 + 0] - qx;
            const float dy = xb[j * 3 + 1] - qy;
            const float dz = xb[j * 3 + 2] - qz;
            const float sx = dx * dx;
            const float sy = dy * dy;
            const float sz = dz * dz;
            d[t] = (sx + sy) + sz;
        }
    }

    // ---- per-lane min ----
    float m = d[0];
#pragma unroll
    for (int t = 1; t < 64; ++t) m = fminf(m, d[t]);

    // ---- bitonic sort the 64 lane-minima (values only, ascending) ----
#pragma unroll
    for (int k = 2; k <= 64; k <<= 1) {
#pragma unroll
        for (int jj = k >> 1; jj > 0; jj >>= 1) {
            const float p = __shfl_xor(m, jj);
            const bool takeMin = (((lane & jj) == 0) == ((lane & k) == 0));
            const bool pLess = p < m;
            m = (pLess == takeMin) ? p : m;
        }
    }
    const float T = __shfl(m, 16);              // 17th smallest lane-min

    // ---- ballot-compact survivors (d <= T) into per-wave LDS ----
    int base = 0;
#pragma unroll
    for (int t = 0; t < 64; ++t) {
        const bool sv = d[t] <= T;
        const unsigned long long mask = __ballot(sv);
        const int below = __popcll(mask & ((1ull << lane) - 1ull));
        const int slot = base + below;
        if (sv && slot < SURV_CAP) {
            const int j = t * 64 + lane;
            sbuf[wave][slot] =
                ((unsigned long long)__float_as_uint(d[t]) << 32) | (unsigned)j;
        }
        base += __popcll(mask);
    }
    const int total = base;

    if (total <= SURV_CAP) {
        // ---- bitonic sort u64 keys (dist, index) ascending ----
        unsigned long long key = (lane < total) ? sbuf[wave][lane] : ~0ull;
#pragma unroll
        for (int k = 2; k <= 64; k <<= 1) {
#pragma unroll
            for (int jj = k >> 1; jj > 0; jj >>= 1) {
                const unsigned long long p = __shfl_xor(key, jj);
                const bool takeMin = (((lane & jj) == 0) == ((lane & k) == 0));
                const bool pLess = p < key;
                key = (pLess == takeMin) ? p : key;
            }
        }
        if (lane >= 1 && lane <= KK)
            knn_idx[(size_t)q * KK + lane - 1] = (int)(key & 0xffffffffu);
    } else {
        // ---- exact fallback: lexicographic successive-min (never runs on
        //      random data; correctness insurance only) ----
        float dp = -1.0f; int jp = -1;
        for (int pass = 0; pass < KK + 1; ++pass) {
            float dmin = 3.4e38f; int jmin = 0x7fffffff;
#pragma unroll
            for (int t = 0; t < 64; ++t) {
                const int j = t * 64 + lane;
                const bool valid = (d[t] > dp) || (d[t] == dp && j > jp);
                const bool less =
                    valid && (d[t] < dmin || (d[t] == dmin && j < jmin));
                dmin = less ? d[t] : dmin;
                jmin = less ? j : jmin;
            }
#pragma unroll
            for (int off = 32; off > 0; off >>= 1) {
                const float d2 = __shfl_xor(dmin, off);
                const int   j2 = __shfl_xor(jmin, off);
                if (d2 < dmin || (d2 == dmin && j2 < jmin)) { dmin = d2; jmin = j2; }
            }
            if (pass >= 1 && lane == 0)
                knn_idx[(size_t)q * KK + pass - 1] = jmin;
            dp = dmin; jp = jmin;
        }
    }
}

// ---------------------------------------------------------------------------
// Kernel B: gather relative coords, 3-layer MLP (relu, relu, none), max over
// the 16 neighbors. One wave per point, lane = output channel. hbuf/gbuf are
// PER-WAVE, so no block barriers in the r-loop: same-wave LDS write->read is
// ordered by the in-order DS pipe (compiler inserts lgkmcnt waits). Only the
// weight staging and the block output staging need __syncthreads.
// ---------------------------------------------------------------------------
__global__ __launch_bounds__(256) void mlp_kernel(const float* __restrict__ xyz,
                                                  const int* __restrict__ knn_idx,
                                                  const float* __restrict__ w1,
                                                  const float* __restrict__ w2,
                                                  const float* __restrict__ w3,
                                                  float* __restrict__ out) {
    __shared__ float w2t[CH * CH];                    // w2t[cp*64 + c] = w2[c][cp]
    __shared__ float w3t[CH * CH];
    __shared__ __align__(16) float hbuf[4][2][CH][20]; // per-wave H1/H2, [c'][nb]
    __shared__ float gbuf[4][KK][4];                  // per-wave rel coords
    __shared__ float obuf[CH][17];                    // block output staging

    const int wave = threadIdx.x >> 6;
    const int lane = threadIdx.x & 63;
    const int base = blockIdx.x * 16;                 // 16 points per block
    const int b = base >> 12;
    const int n0 = base & (NPTS - 1);
    const float* xb = xyz + (size_t)b * NPTS * 3;

    for (int s = threadIdx.x; s < CH * CH; s += 256) {
        const int c = s >> 6, cp = s & 63;
        w2t[cp * CH + c] = w2[s];
        w3t[cp * CH + c] = w3[s];
    }
    const float w1c0 = w1[lane * 3 + 0];
    const float w1c1 = w1[lane * 3 + 1];
    const float w1c2 = w1[lane * 3 + 2];
    __syncthreads();

    for (int r = 0; r < 4; ++r) {
        const int p = wave * 4 + r;                   // point slot 0..15
        const int n = n0 + p;
        // ---- gather relative neighbor coords (lanes 0..15) ----
        if (lane < KK) {
            const int j = knn_idx[((size_t)b * NPTS + n) * KK + lane];
            const float px = xb[n * 3 + 0];
            const float py = xb[n * 3 + 1];
            const float pz = xb[n * 3 + 2];
            gbuf[wave][lane][0] = xb[j * 3 + 0] - px;
            gbuf[wave][lane][1] = xb[j * 3 + 1] - py;
            gbuf[wave][lane][2] = xb[j * 3 + 2] - pz;
        }
        // ---- layer 1: h1[c][nb] = relu(W1 row c . g[nb]) ----
        float h1[KK];
#pragma unroll
        for (int nb = 0; nb < KK; ++nb) {
            const float gx = gbuf[wave][nb][0];
            const float gy = gbuf[wave][nb][1];
            const float gz = gbuf[wave][nb][2];
            const float v = w1c0 * gx + w1c1 * gy + w1c2 * gz;
            h1[nb] = v > 0.f ? v : 0.f;
        }
#pragma unroll
        for (int nb4 = 0; nb4 < 4; ++nb4) {
            *(float4*)&hbuf[wave][0][lane][nb4 * 4] =
                make_float4(h1[nb4 * 4 + 0], h1[nb4 * 4 + 1],
                            h1[nb4 * 4 + 2], h1[nb4 * 4 + 3]);
        }
        // ---- layer 2: h2 = relu(W2 h1) ----
        float h2[KK];
#pragma unroll
        for (int nb = 0; nb < KK; ++nb) h2[nb] = 0.f;
#pragma unroll 4
        for (int cp = 0; cp < CH; ++cp) {
            const float w = w2t[cp * CH + lane];      // per-lane, conflict-free
            float a[KK];
            *(float4*)&a[0]  = *(const float4*)&hbuf[wave][0][cp][0];   // broadcast
            *(float4*)&a[4]  = *(const float4*)&hbuf[wave][0][cp][4];
            *(float4*)&a[8]  = *(const float4*)&hbuf[wave][0][cp][8];
            *(float4*)&a[12] = *(const float4*)&hbuf[wave][0][cp][12];
#pragma unroll
            for (int nb = 0; nb < KK; ++nb) h2[nb] += w * a[nb];
        }
#pragma unroll
        for (int nb = 0; nb < KK; ++nb) h2[nb] = h2[nb] > 0.f ? h2[nb] : 0.f;
#pragma unroll
        for (int nb4 = 0; nb4 < 4; ++nb4) {
            *(float4*)&hbuf[wave][1][lane][nb4 * 4] =
                make_float4(h2[nb4 * 4 + 0], h2[nb4 * 4 + 1],
                            h2[nb4 * 4 + 2], h2[nb4 * 4 + 3]);
        }
        // ---- layer 3: h3 = W3 h2 (no relu), then max over neighbors ----
        float h3[KK];
#pragma unroll
        for (int nb = 0; nb < KK; ++nb) h3[nb] = 0.f;
#pragma unroll 4
        for (int cp = 0; cp < CH; ++cp) {
            const float w = w3t[cp * CH + lane];
            float a[KK];
            *(float4*)&a[0]  = *(const float4*)&hbuf[wave][1][cp][0];
            *(float4*)&a[4]  = *(const float4*)&hbuf[wave][1][cp][4];
            *(float4*)&a[8]  = *(const float4*)&hbuf[wave][1][cp][8];
            *(float4*)&a[12] = *(const float4*)&hbuf[wave][1][cp][12];
#pragma unroll
            for (int nb = 0; nb < KK; ++nb) h3[nb] += w * a[nb];
        }
        float mx = h3[0];
#pragma unroll
        for (int nb = 1; nb < KK; ++nb) mx = fmaxf(mx, h3[nb]);
        obuf[lane][p] = mx;
    }
    __syncthreads();
    // coalesced-ish output store: out[(b*CH + c)*NPTS + n0 + p]
    for (int s = threadIdx.x; s < CH * 16; s += 256) {
        const int c = s >> 4, pp = s & 15;
        out[((size_t)(b * CH + c)) * NPTS + n0 + pp] = obuf[c][pp];
    }
}

extern "C" void kernel_launch(void* const* d_in, const int* in_sizes, int n_in,
                              void* d_out, int out_size, void* d_ws, size_t ws_size,
                              hipStream_t stream) {
    (void)in_sizes; (void)n_in; (void)out_size; (void)ws_size;
    const float* xyz = (const float*)d_in[0];
    const float* w1  = (const float*)d_in[1];
    const float* w2  = (const float*)d_in[2];
    const float* w3  = (const float*)d_in[3];
    // d_in[4] is k (always 16 for this problem)
    int*   knn = (int*)d_ws;                 // BATCH*NPTS*KK ints = 1 MiB
    float* out = (float*)d_out;

    knn_kernel<<<BATCH * NPTS / 4, 256, 0, stream>>>(xyz, knn);
    mlp_kernel<<<BATCH * NPTS / 16, 256, 0, stream>>>(xyz, knn, w1, w2, w3, out);
}